// Round 1
// baseline (7322.874 us; speedup 1.0000x reference)
//
#include <hip/hip_runtime.h>
#include <math.h>

#define GRID 256
#define TPB  256
#define BB   64
#define HH   1024
#define VV   32000
#define TT   13

typedef float f32x4 __attribute__((ext_vector_type(4)));
typedef __bf16 bf16x8 __attribute__((ext_vector_type(8)));
typedef unsigned short u16x8 __attribute__((ext_vector_type(8)));

struct KArgs {
  const float *enc, *emb, *wih, *whh, *bih, *bhh, *wout, *bout;
  float *out;
  unsigned *ctrl;
  float *hrm;            // [2][BB][HH] f32 h (row-major)
  unsigned short *hbf;   // [2][BB][HH] bf16 h
  float *xrm;            // [BB][HH] f32 x = relu(emb[tok])
  float *lbuf;           // [BB][VV] raw logits for current step
  float *logZ;           // [TT][BB]
  unsigned short *wbf;   // [VV][HH] bf16 w_out cache (may be null)
  int cachew;
};

union SMem {
  unsigned char abuf[131072];     // 128 KiB swizzled bf16 A-tile (h)
  float wlds[24 * 1024];          // 96 KiB GRU weight rows
  struct {
    float m[4]; float s[4]; int idx[4];
    float M; int cnt; int tok; int cand[64];
  } red;
};

__device__ __forceinline__ unsigned short f2bf(float f) {
  unsigned u = __float_as_uint(f);
  u = (u + 0x7fffu + ((u >> 16) & 1u)) >> 16;   // RNE
  return (unsigned short)u;
}

__device__ __forceinline__ void gsync(unsigned* cnt, unsigned target) {
  __syncthreads();
  if (threadIdx.x == 0) {
    __hip_atomic_fetch_add(cnt, 1u, __ATOMIC_RELEASE, __HIP_MEMORY_SCOPE_AGENT);
    while (__hip_atomic_load(cnt, __ATOMIC_ACQUIRE, __HIP_MEMORY_SCOPE_AGENT) < target)
      __builtin_amdgcn_s_sleep(2);
  }
  __syncthreads();
}

__global__ __launch_bounds__(TPB, 1) void decoder_kernel(KArgs a) {
  __shared__ SMem sm;
  const int blk = blockIdx.x, tid = threadIdx.x;
  const int lane = tid & 63, wv = tid >> 6;
  unsigned barNo = 0;

  // ---------------- init: h0 = encoder_hidden, x = relu(emb[PAD=0]) ----------------
  {
    const int gid = blk * TPB + tid;          // [0, 65536)
    a.hrm[gid] = a.enc[gid];                  // buf 0, [b][k] layout matches
    const int k = gid & (HH - 1);
    const float e = a.emb[k];                 // token 0 row, broadcast over b
    a.xrm[gid] = e > 0.f ? e : 0.f;
  }
  gsync(a.ctrl, ++barNo * GRID);

  for (int t = 0; t < TT; ++t) {
    const int p = t & 1;
    const float* hsrc = a.hrm + (size_t)p * BB * HH;
    float* hdst = a.hrm + (size_t)(p ^ 1) * BB * HH;
    unsigned short* hbfdst = a.hbf + (size_t)(p ^ 1) * BB * HH;

    // ============ Phase A: write out step t-1, then GRU ============
    if (t > 0) {
      const int ob = blk >> 2;
      const float lz = a.logZ[(t - 1) * BB + ob];
      const f32x4* src = (const f32x4*)(a.lbuf + (size_t)ob * VV) + (blk & 3) * 2000;
      f32x4* dst = (f32x4*)(a.out + (size_t)(ob * TT + (t - 1)) * VV) + (blk & 3) * 2000;
      for (int i = tid; i < 2000; i += TPB) {
        f32x4 v = src[i];
        v = v - lz;
        dst[i] = v;
      }
    }
    {
      const int j0 = blk * 4;
      for (int q = tid; q < 24 * 256; q += TPB) {
        const int r = q >> 8, f4 = q & 255;
        const int c = r & 3, g = r >> 2;
        const float* srcw = (g < 3 ? a.wih : a.whh)
            + (size_t)((g % 3) * HH + j0 + c) * HH + f4 * 4;
        *(f32x4*)&sm.wlds[r * HH + f4 * 4] = *(const f32x4*)srcw;
      }
      __syncthreads();
      const int b = tid & 63, c = tid >> 6;
      const int j = j0 + c;
      float air = a.bih[j], aiz = a.bih[HH + j], ain = a.bih[2 * HH + j];
      float ahr = a.bhh[j], ahz = a.bhh[HH + j], ahn = a.bhh[2 * HH + j];
      const float* xr = a.xrm + (size_t)b * HH;
      const float* hr = hsrc + (size_t)b * HH;
      const float* wir = &sm.wlds[(0 * 4 + c) * HH];
      const float* wiz = &sm.wlds[(1 * 4 + c) * HH];
      const float* win = &sm.wlds[(2 * 4 + c) * HH];
      const float* whr = &sm.wlds[(3 * 4 + c) * HH];
      const float* whz = &sm.wlds[(4 * 4 + c) * HH];
      const float* whn = &sm.wlds[(5 * 4 + c) * HH];
      for (int k = 0; k < HH; k += 4) {
        const f32x4 x4 = *(const f32x4*)(xr + k);
        const f32x4 h4 = *(const f32x4*)(hr + k);
        const f32x4 v0 = *(const f32x4*)(wir + k);
        const f32x4 v1 = *(const f32x4*)(wiz + k);
        const f32x4 v2 = *(const f32x4*)(win + k);
        const f32x4 v3 = *(const f32x4*)(whr + k);
        const f32x4 v4 = *(const f32x4*)(whz + k);
        const f32x4 v5 = *(const f32x4*)(whn + k);
        #pragma unroll
        for (int u = 0; u < 4; ++u) {
          air += x4[u] * v0[u]; aiz += x4[u] * v1[u]; ain += x4[u] * v2[u];
          ahr += h4[u] * v3[u]; ahz += h4[u] * v4[u]; ahn += h4[u] * v5[u];
        }
      }
      const float r_ = 1.f / (1.f + expf(-(air + ahr)));
      const float z_ = 1.f / (1.f + expf(-(aiz + ahz)));
      const float n_ = tanhf(ain + r_ * ahn);
      const float hold = hr[j];
      const float hnew = (1.f - z_) * n_ + z_ * hold;
      hdst[(size_t)b * HH + j] = hnew;
      hbfdst[(size_t)b * HH + j] = f2bf(hnew);
    }
    gsync(a.ctrl, ++barNo * GRID);

    // ============ Phase B: logits = h @ w_out^T + b_out (bf16 MFMA) ============
    if (blk < 250) {
      const unsigned short* hb = a.hbf + (size_t)(p ^ 1) * BB * HH;
      for (int it = 0; it < 32; ++it) {
        const int off = it * 4096 + tid * 16;
        const uint4 v = *(const uint4*)((const unsigned char*)hb + off);
        const int row = off >> 11;
        *(uint4*)(sm.abuf + (off ^ ((row & 7) << 4))) = v;
      }
      __syncthreads();
      const int n0 = blk * 128 + wv * 32;
      const int cl = lane & 15;
      const int kk = (lane >> 4) * 8;
      f32x4 acc[4][2];
      #pragma unroll
      for (int i0 = 0; i0 < 4; ++i0) {
        acc[i0][0] = (f32x4){0.f, 0.f, 0.f, 0.f};
        acc[i0][1] = (f32x4){0.f, 0.f, 0.f, 0.f};
      }
      const bool f32src = (!a.cachew) || (t == 0);
      const bool storebf = a.cachew && (t == 0);
      for (int k0 = 0; k0 < HH; k0 += 32) {
        bf16x8 bfr[2];
        #pragma unroll
        for (int ct = 0; ct < 2; ++ct) {
          const size_t boff = (size_t)(n0 + ct * 16 + cl) * HH + (k0 + kk);
          if (!f32src) {
            bfr[ct] = *(const bf16x8*)(a.wbf + boff);
          } else {
            const float* wp = a.wout + boff;
            const f32x4 w0 = *(const f32x4*)wp;
            const f32x4 w1 = *(const f32x4*)(wp + 4);
            union { u16x8 u; bf16x8 b; } cv;
            #pragma unroll
            for (int u2 = 0; u2 < 4; ++u2) {
              cv.u[u2] = f2bf(w0[u2]); cv.u[4 + u2] = f2bf(w1[u2]);
            }
            bfr[ct] = cv.b;
            if (storebf) *(u16x8*)(a.wbf + boff) = cv.u;
          }
        }
        bf16x8 afr[4];
        #pragma unroll
        for (int rt = 0; rt < 4; ++rt) {
          const int row = rt * 16 + cl;
          const int byte = row * 2048 + (k0 + kk) * 2;
          afr[rt] = *(const bf16x8*)(sm.abuf + (byte ^ ((row & 7) << 4)));
        }
        #pragma unroll
        for (int rt = 0; rt < 4; ++rt)
          #pragma unroll
          for (int ct = 0; ct < 2; ++ct)
            acc[rt][ct] = __builtin_amdgcn_mfma_f32_16x16x32_bf16(
                afr[rt], bfr[ct], acc[rt][ct], 0, 0, 0);
      }
      #pragma unroll
      for (int ct = 0; ct < 2; ++ct) {
        const int col = n0 + ct * 16 + cl;
        const float bo = a.bout[col];
        #pragma unroll
        for (int rt = 0; rt < 4; ++rt)
          #pragma unroll
          for (int rg = 0; rg < 4; ++rg) {
            const int row = rt * 16 + (lane >> 4) * 4 + rg;
            a.lbuf[(size_t)row * VV + col] = acc[rt][ct][rg] + bo;
          }
      }
    }
    gsync(a.ctrl, ++barNo * GRID);

    // ============ Phase C: logsumexp + exact-argmax recheck + next x ============
    if (blk < BB) {
      const int b = blk;
      const float* row = a.lbuf + (size_t)b * VV;
      float m, s; int idx;
      { const float v = row[tid]; m = v; s = 1.f; idx = tid; }
      for (int i = tid + TPB; i < VV; i += TPB) {
        const float v = row[i];
        if (v > m) { s = s * __expf(m - v) + 1.f; m = v; idx = i; }
        else s += __expf(v - m);
      }
      #pragma unroll
      for (int d = 1; d < 64; d <<= 1) {
        const float om = __shfl_xor(m, d, 64);
        const float os = __shfl_xor(s, d, 64);
        const int oi = __shfl_xor(idx, d, 64);
        const float mn = fmaxf(m, om);
        s = s * __expf(m - mn) + os * __expf(om - mn);
        idx = (om > m) ? oi : ((om == m) ? (oi < idx ? oi : idx) : idx);
        m = mn;
      }
      if (lane == 0) { sm.red.m[wv] = m; sm.red.s[wv] = s; sm.red.idx[wv] = idx; }
      __syncthreads();
      if (tid == 0) {
        float M = sm.red.m[0]; float S = sm.red.s[0]; int I = sm.red.idx[0];
        for (int w = 1; w < 4; ++w) {
          const float om = sm.red.m[w], os = sm.red.s[w]; const int oi = sm.red.idx[w];
          const float mn = fmaxf(M, om);
          S = S * __expf(M - mn) + os * __expf(om - mn);
          I = (om > M) ? oi : ((om == M) ? (oi < I ? oi : I) : I);
          M = mn;
        }
        a.logZ[t * BB + b] = M + logf(S);
        sm.red.M = M; sm.red.cnt = 0; sm.red.tok = I;
      }
      __syncthreads();
      if (t < TT - 1) {
        const float thr = sm.red.M - 0.05f;
        for (int i = tid; i < VV; i += TPB)
          if (row[i] >= thr) {
            const int c = atomicAdd(&sm.red.cnt, 1);
            if (c < 64) sm.red.cand[c] = i;
          }
        __syncthreads();
        const int nc = sm.red.cnt < 64 ? sm.red.cnt : 64;
        if (wv == 0) {
          const float* hrow = hdst + (size_t)b * HH;
          float best = -1e30f; int bi = 0x7fffffff;
          for (int ci = 0; ci < nc; ++ci) {
            const int v = sm.red.cand[ci];
            const float* wrow = a.wout + (size_t)v * HH;
            float ss = 0.f;
            #pragma unroll
            for (int jj = 0; jj < 16; ++jj)
              ss += hrow[lane * 16 + jj] * wrow[lane * 16 + jj];
            #pragma unroll
            for (int d = 1; d < 64; d <<= 1) ss += __shfl_xor(ss, d, 64);
            ss += a.bout[v];
            if (ss > best || (ss == best && v < bi)) { best = ss; bi = v; }
          }
          if (lane == 0) sm.red.tok = bi;
        }
        __syncthreads();
        const int tok = sm.red.tok;
        for (int k = tid; k < HH; k += TPB) {
          const float e = a.emb[(size_t)tok * HH + k];
          a.xrm[(size_t)b * HH + k] = e > 0.f ? e : 0.f;
        }
      }
    }
    gsync(a.ctrl, ++barNo * GRID);
  }

  // ---------------- final: write out step 12 + h_final ----------------
  {
    const int ob = blk >> 2;
    const float lz = a.logZ[(TT - 1) * BB + ob];
    const f32x4* src = (const f32x4*)(a.lbuf + (size_t)ob * VV) + (blk & 3) * 2000;
    f32x4* dst = (f32x4*)(a.out + (size_t)(ob * TT + (TT - 1)) * VV) + (blk & 3) * 2000;
    for (int i = tid; i < 2000; i += TPB) {
      f32x4 v = src[i];
      v = v - lz;
      dst[i] = v;
    }
    const int gid = blk * TPB + tid;
    a.out[(size_t)BB * TT * VV + gid] = a.hrm[(size_t)BB * HH + gid];  // h buf 1
  }
}

extern "C" void kernel_launch(void* const* d_in, const int* in_sizes, int n_in,
                              void* d_out, int out_size, void* d_ws, size_t ws_size,
                              hipStream_t stream) {
  KArgs a;
  a.enc  = (const float*)d_in[1];
  a.emb  = (const float*)d_in[2];
  a.wih  = (const float*)d_in[3];
  a.whh  = (const float*)d_in[4];
  a.bih  = (const float*)d_in[5];
  a.bhh  = (const float*)d_in[6];
  a.wout = (const float*)d_in[7];
  a.bout = (const float*)d_in[8];
  a.out  = (float*)d_out;

  char* ws = (char*)d_ws;
  const size_t o_hrm  = 256;
  const size_t o_hbf  = o_hrm  + (size_t)2 * BB * HH * 4;
  const size_t o_xrm  = o_hbf  + (size_t)2 * BB * HH * 2;
  const size_t o_lbuf = o_xrm  + (size_t)BB * HH * 4;
  const size_t o_logZ = o_lbuf + (size_t)BB * VV * 4;
  const size_t o_wbf  = o_logZ + (size_t)TT * BB * 4;
  const size_t need_cache = o_wbf + (size_t)VV * HH * 2;

  a.ctrl = (unsigned*)ws;
  a.hrm  = (float*)(ws + o_hrm);
  a.hbf  = (unsigned short*)(ws + o_hbf);
  a.xrm  = (float*)(ws + o_xrm);
  a.lbuf = (float*)(ws + o_lbuf);
  a.logZ = (float*)(ws + o_logZ);
  if (ws_size >= need_cache) {
    a.wbf = (unsigned short*)(ws + o_wbf);
    a.cachew = 1;
  } else {
    a.wbf = nullptr;
    a.cachew = 0;
  }

  hipMemsetAsync(d_ws, 0, 256, stream);
  hipLaunchKernelGGL(decoder_kernel, dim3(GRID), dim3(TPB), 0, stream, a);
}

// Round 2
// 2011.077 us; speedup vs baseline: 3.6413x; 3.6413x over previous
//
#include <hip/hip_runtime.h>
#include <math.h>

#define BB 64
#define HH 1024
#define VV 32000
#define TT 13

typedef float f32x4 __attribute__((ext_vector_type(4)));
typedef __bf16 bf16x8 __attribute__((ext_vector_type(8)));

__device__ __forceinline__ unsigned short f2bf(float f) {
  unsigned u = __float_as_uint(f);
  u = (u + 0x7fffu + ((u >> 16) & 1u)) >> 16;   // RNE
  return (unsigned short)u;
}

// ---------------- init: h0 = encoder_hidden, x0 = relu(emb[PAD=0]) ----------------
__global__ __launch_bounds__(1024) void k_init(const float* __restrict__ enc,
                                               const float* __restrict__ emb,
                                               float* __restrict__ hrm,
                                               float* __restrict__ xrm) {
  const int g = blockIdx.x * 1024 + threadIdx.x;   // grid 64 -> [0,65536)
  hrm[g] = enc[g];
  const float e = emb[threadIdx.x];                // token 0 row
  xrm[g] = e > 0.f ? e : 0.f;
}

// ---------------- one-time w_out f32 -> bf16 cache ----------------
__global__ __launch_bounds__(256) void k_wconv(const float* __restrict__ w,
                                               unsigned short* __restrict__ o) {
  const int n4 = VV * HH / 4;
  for (int i = blockIdx.x * 256 + threadIdx.x; i < n4; i += gridDim.x * 256) {
    const f32x4 v = ((const f32x4*)w)[i];
    ushort4 u;
    u.x = f2bf(v[0]); u.y = f2bf(v[1]); u.z = f2bf(v[2]); u.w = f2bf(v[3]);
    ((ushort4*)o)[i] = u;
  }
}

// ---------------- GRU cell: f32 VALU, lane = k (coalesced) ----------------
// grid 256, block 1024 (16 waves). Block owns 4 h-columns j = blk*4 + c.
// Wave (c = wv&3, bq = wv>>2) handles 16 batch rows x 6 gate dots, lanes split K.
__global__ __launch_bounds__(1024, 1) void k_gru(
    const float* __restrict__ xrm, const float* __restrict__ hsrc,
    const float* __restrict__ wih, const float* __restrict__ whh,
    const float* __restrict__ bih, const float* __restrict__ bhh,
    float* __restrict__ hdst, unsigned short* __restrict__ hbfdst) {
  __shared__ float wlds[24 * HH];      // 96 KiB: 6 gate-rows x 4 cols
  __shared__ float gsum[BB * 4 * 6];   // 6 KiB partial results
  const int tid = threadIdx.x, blk = blockIdx.x;
  const int lane = tid & 63, wv = tid >> 6;

  for (int q = tid; q < 24 * 256; q += 1024) {          // stage weights, coalesced
    const int r = q >> 8, f4 = q & 255;
    const int c = r & 3, g = r >> 2;
    const float* src = (g < 3 ? wih : whh) + (size_t)((g % 3) * HH + blk * 4 + c) * HH + f4 * 4;
    *(f32x4*)&wlds[r * HH + f4 * 4] = *(const f32x4*)src;
  }
  __syncthreads();

  const int c = wv & 3, bq = wv >> 2;
  const int ko = lane * 16;                              // lane's K-chunk
  for (int bi = 0; bi < 16; ++bi) {
    const int b = bq * 16 + bi;
    const float* xr = xrm + (size_t)b * HH + ko;
    const float* hr = hsrc + (size_t)b * HH + ko;
    f32x4 xv[4], hv[4];
    #pragma unroll
    for (int u = 0; u < 4; ++u) {
      xv[u] = *(const f32x4*)(xr + u * 4);
      hv[u] = *(const f32x4*)(hr + u * 4);
    }
    float p[6];
    #pragma unroll
    for (int g = 0; g < 6; ++g) {
      const float* wr = &wlds[(g * 4 + c) * HH + ko];
      f32x4 acc = {0.f, 0.f, 0.f, 0.f};
      #pragma unroll
      for (int u = 0; u < 4; ++u) {
        const f32x4 w4 = *(const f32x4*)(wr + u * 4);
        acc += (g < 3 ? xv[u] : hv[u]) * w4;
      }
      p[g] = acc[0] + acc[1] + acc[2] + acc[3];
    }
    #pragma unroll
    for (int g = 0; g < 6; ++g) {
      float s = p[g];
      #pragma unroll
      for (int d = 1; d < 64; d <<= 1) s += __shfl_xor(s, d, 64);
      if (lane == 0) gsum[(b * 4 + c) * 6 + g] = s;
    }
  }
  __syncthreads();

  if (tid < 256) {
    const int b = tid & 63, cc = tid >> 6;
    const int j = blk * 4 + cc;
    const float* gs = &gsum[(b * 4 + cc) * 6];
    const float air = bih[j] + gs[0], aiz = bih[HH + j] + gs[1], ain = bih[2 * HH + j] + gs[2];
    const float ahr = bhh[j] + gs[3], ahz = bhh[HH + j] + gs[4], ahn = bhh[2 * HH + j] + gs[5];
    const float r_ = 1.f / (1.f + __expf(-(air + ahr)));
    const float z_ = 1.f / (1.f + __expf(-(aiz + ahz)));
    const float n_ = tanhf(ain + r_ * ahn);
    const float hold = hsrc[(size_t)b * HH + j];
    const float hnew = (1.f - z_) * n_ + z_ * hold;
    hdst[(size_t)b * HH + j] = hnew;
    hbfdst[(size_t)b * HH + j] = f2bf(hnew);
  }
}

// ---------------- logits = h @ w_out^T + b_out (bf16 MFMA) ----------------
// grid 250, block 512 (8 waves). Wave owns one 16-col tile, full M=64, K=1024.
__global__ __launch_bounds__(512, 1) void k_logits(
    const unsigned short* __restrict__ hb,   // bf16 h [BB][HH]
    const unsigned short* __restrict__ wbf,  // bf16 w_out cache (or unused)
    const float* __restrict__ wout,
    const float* __restrict__ bout,
    float* __restrict__ lbuf, int cachew) {
  __shared__ __attribute__((aligned(16))) unsigned char abuf[131072];
  const int tid = threadIdx.x, blk = blockIdx.x;
  const int lane = tid & 63, wv = tid >> 6;

  for (int it = 0; it < 16; ++it) {                      // stage h tile, swizzled
    const int off = it * 8192 + tid * 16;
    const uint4 v = *(const uint4*)((const unsigned char*)hb + off);
    const int row = off >> 11;
    *(uint4*)(abuf + (off ^ ((row & 7) << 4))) = v;
  }
  __syncthreads();

  const int n0 = blk * 128 + wv * 16;
  const int cl = lane & 15, kk = (lane >> 4) * 8;
  f32x4 acc[4];
  acc[0] = acc[1] = acc[2] = acc[3] = (f32x4){0.f, 0.f, 0.f, 0.f};

  for (int k0 = 0; k0 < HH; k0 += 32) {
    bf16x8 bfr;
    const size_t boff = (size_t)(n0 + cl) * HH + k0 + kk;
    if (cachew) {
      bfr = *(const bf16x8*)(wbf + boff);
    } else {
      const f32x4 w0 = *(const f32x4*)(wout + boff);
      const f32x4 w1 = *(const f32x4*)(wout + boff + 4);
      union { unsigned short u[8]; bf16x8 b; } cv;
      #pragma unroll
      for (int u2 = 0; u2 < 4; ++u2) { cv.u[u2] = f2bf(w0[u2]); cv.u[4 + u2] = f2bf(w1[u2]); }
      bfr = cv.b;
    }
    #pragma unroll
    for (int rt = 0; rt < 4; ++rt) {
      const int row = rt * 16 + cl;
      const int byte = row * 2048 + (k0 + kk) * 2;
      const bf16x8 afr = *(const bf16x8*)(abuf + (byte ^ ((row & 7) << 4)));
      acc[rt] = __builtin_amdgcn_mfma_f32_16x16x32_bf16(afr, bfr, acc[rt], 0, 0, 0);
    }
  }

  const int col = n0 + cl;
  const float bo = bout[col];
  #pragma unroll
  for (int rt = 0; rt < 4; ++rt)
    #pragma unroll
    for (int rg = 0; rg < 4; ++rg) {
      const int row = rt * 16 + (lane >> 4) * 4 + rg;
      lbuf[(size_t)row * VV + col] = acc[rt][rg] + bo;
    }
}

// ---------------- logsumexp + exact argmax recheck + out write + next x ----------------
// grid 64 (one block per batch row), block 1024.
__global__ __launch_bounds__(1024, 1) void k_reduce(
    const float* __restrict__ lbuf, const float* __restrict__ wout,
    const float* __restrict__ bout, const float* __restrict__ emb,
    const float* __restrict__ hnew,   // h_{t+1} [BB][HH] f32
    const float* __restrict__ hfin,   // h buffer 1 (final h) for t==12
    float* __restrict__ out, float* __restrict__ xrm, int t) {
  __shared__ struct {
    float rowc[VV];                   // 125 KiB row cache
    float m[16]; float s[16]; int idx[16];
    float M, LZ; int cnt, tok; int cand[62];
  } sm;
  const int tid = threadIdx.x, b = blockIdx.x;
  const int lane = tid & 63, wv = tid >> 6;
  const float* row = lbuf + (size_t)b * VV;

  float m, s; int idx;
  { const float v = row[tid]; sm.rowc[tid] = v; m = v; s = 1.f; idx = tid; }
  for (int i = tid + 1024; i < VV; i += 1024) {
    const float v = row[i];
    sm.rowc[i] = v;
    if (v > m) { s = s * __expf(m - v) + 1.f; m = v; idx = i; }
    else s += __expf(v - m);
  }
  #pragma unroll
  for (int d = 1; d < 64; d <<= 1) {
    const float om = __shfl_xor(m, d, 64);
    const float os = __shfl_xor(s, d, 64);
    const int oi = __shfl_xor(idx, d, 64);
    const float mn = fmaxf(m, om);
    s = s * __expf(m - mn) + os * __expf(om - mn);
    idx = (om > m) ? oi : ((om == m) ? (oi < idx ? oi : idx) : idx);
    m = mn;
  }
  if (lane == 0) { sm.m[wv] = m; sm.s[wv] = s; sm.idx[wv] = idx; }
  __syncthreads();
  if (tid == 0) {
    float M = sm.m[0], S = sm.s[0]; int I = sm.idx[0];
    for (int w = 1; w < 16; ++w) {
      const float om = sm.m[w], os = sm.s[w]; const int oi = sm.idx[w];
      const float mn = fmaxf(M, om);
      S = S * __expf(M - mn) + os * __expf(om - mn);
      I = (om > M) ? oi : ((om == M) ? (oi < I ? oi : I) : I);
      M = mn;
    }
    sm.M = M; sm.LZ = M + logf(S); sm.cnt = 0; sm.tok = I;
  }
  __syncthreads();

  if (t < TT - 1) {
    const float thr = sm.M - 0.05f;                      // candidates near approx max
    for (int i = tid; i < VV; i += 1024)
      if (sm.rowc[i] >= thr) {
        const int c = atomicAdd(&sm.cnt, 1);
        if (c < 62) sm.cand[c] = i;
      }
    __syncthreads();
    if (wv == 0) {                                       // exact f32 recheck
      const int nc = sm.cnt < 62 ? sm.cnt : 62;
      const float* hrow = hnew + (size_t)b * HH;
      f32x4 h4[4];
      #pragma unroll
      for (int u = 0; u < 4; ++u) h4[u] = *(const f32x4*)(hrow + lane * 16 + u * 4);
      float best = -1e30f; int bi = 0x7fffffff;
      for (int ci = 0; ci < nc; ++ci) {
        const int v = sm.cand[ci];
        const float* wrow = wout + (size_t)v * HH + lane * 16;
        float ss = 0.f;
        #pragma unroll
        for (int u = 0; u < 4; ++u) {
          const f32x4 w4 = *(const f32x4*)(wrow + u * 4);
          ss += h4[u][0] * w4[0] + h4[u][1] * w4[1] + h4[u][2] * w4[2] + h4[u][3] * w4[3];
        }
        #pragma unroll
        for (int d = 1; d < 64; d <<= 1) ss += __shfl_xor(ss, d, 64);
        ss += bout[v];
        if (ss > best || (ss == best && v < bi)) { best = ss; bi = v; }
      }
      if (lane == 0) sm.tok = bi;
    }
    __syncthreads();
    const int tok = sm.tok;                              // next input token
    const float e = emb[(size_t)tok * HH + tid];
    xrm[(size_t)b * HH + tid] = e > 0.f ? e : 0.f;
  }

  const float lz = sm.LZ;                                // log_softmax + store
  for (int i = tid; i < VV; i += 1024)
    out[((size_t)b * TT + t) * VV + i] = sm.rowc[i] - lz;
  if (t == TT - 1)
    out[(size_t)BB * TT * VV + (size_t)b * HH + tid] = hfin[(size_t)b * HH + tid];
}

extern "C" void kernel_launch(void* const* d_in, const int* in_sizes, int n_in,
                              void* d_out, int out_size, void* d_ws, size_t ws_size,
                              hipStream_t stream) {
  const float* enc  = (const float*)d_in[1];
  const float* emb  = (const float*)d_in[2];
  const float* wih  = (const float*)d_in[3];
  const float* whh  = (const float*)d_in[4];
  const float* bih  = (const float*)d_in[5];
  const float* bhh  = (const float*)d_in[6];
  const float* wout = (const float*)d_in[7];
  const float* bout = (const float*)d_in[8];
  float* out = (float*)d_out;

  char* ws = (char*)d_ws;
  size_t off = 0;
  float* hrm = (float*)(ws + off);          off += (size_t)2 * BB * HH * 4;
  unsigned short* hbf = (unsigned short*)(ws + off); off += (size_t)2 * BB * HH * 2;
  float* xrm = (float*)(ws + off);          off += (size_t)BB * HH * 4;
  float* lbuf = (float*)(ws + off);         off += (size_t)BB * VV * 4;
  unsigned short* wbf = (unsigned short*)(ws + off);
  const int cachew = (ws_size >= off + (size_t)VV * HH * 2) ? 1 : 0;

  hipLaunchKernelGGL(k_init, dim3(64), dim3(1024), 0, stream, enc, emb, hrm, xrm);
  if (cachew)
    hipLaunchKernelGGL(k_wconv, dim3(2048), dim3(256), 0, stream, wout, wbf);

  for (int t = 0; t < TT; ++t) {
    const int p = t & 1;
    const float* hsrc = hrm + (size_t)p * BB * HH;
    float* hdst = hrm + (size_t)(p ^ 1) * BB * HH;
    unsigned short* hbfd = hbf + (size_t)(p ^ 1) * BB * HH;
    hipLaunchKernelGGL(k_gru, dim3(256), dim3(1024), 0, stream,
                       xrm, hsrc, wih, whh, bih, bhh, hdst, hbfd);
    hipLaunchKernelGGL(k_logits, dim3(250), dim3(512), 0, stream,
                       hbfd, wbf, wout, bout, lbuf, cachew);
    hipLaunchKernelGGL(k_reduce, dim3(64), dim3(1024), 0, stream,
                       lbuf, wout, bout, emb, hdst, hrm + (size_t)BB * HH, out, xrm, t);
  }
}

// Round 3
// 1748.593 us; speedup vs baseline: 4.1879x; 1.1501x over previous
//
#include <hip/hip_runtime.h>
#include <math.h>

#define BB 64
#define HH 1024
#define VV 32000
#define TT 13

typedef float f32x4 __attribute__((ext_vector_type(4)));
typedef __bf16 bf16x8 __attribute__((ext_vector_type(8)));

__device__ __forceinline__ unsigned short f2bf(float f) {   // RNE
  unsigned u = __float_as_uint(f);
  u = (u + 0x7fffu + ((u >> 16) & 1u)) >> 16;
  return (unsigned short)u;
}
__device__ __forceinline__ float bf2f(unsigned short s) {
  return __uint_as_float(((unsigned)s) << 16);
}

// ---------------- init: h0 + splits, x0 = relu(emb[PAD=0]) + splits ----------------
__global__ __launch_bounds__(1024) void k_init(
    const float* __restrict__ enc, const float* __restrict__ emb,
    float* __restrict__ hrm, unsigned short* __restrict__ hhi,
    unsigned short* __restrict__ hlo, unsigned short* __restrict__ xhi,
    unsigned short* __restrict__ xlo) {
  const int g = blockIdx.x * 1024 + threadIdx.x;   // grid 64 -> [0,65536)
  const float h = enc[g];
  hrm[g] = h;
  const unsigned short hh16 = f2bf(h);
  hhi[g] = hh16;
  hlo[g] = f2bf(h - bf2f(hh16));
  float e = emb[threadIdx.x];                      // token 0 row
  e = e > 0.f ? e : 0.f;
  const unsigned short eh = f2bf(e);
  xhi[g] = eh;
  xlo[g] = f2bf(e - bf2f(eh));
}

// ---------------- one-time w_out f32 -> bf16 cache ----------------
__global__ __launch_bounds__(256) void k_wconv(const float* __restrict__ w,
                                               unsigned short* __restrict__ o) {
  const int n4 = VV * HH / 4;
  for (int i = blockIdx.x * 256 + threadIdx.x; i < n4; i += gridDim.x * 256) {
    const f32x4 v = ((const f32x4*)w)[i];
    ushort4 u;
    u.x = f2bf(v[0]); u.y = f2bf(v[1]); u.z = f2bf(v[2]); u.w = f2bf(v[3]);
    ((ushort4*)o)[i] = u;
  }
}

// ---------------- GRU: split-bf16 MFMA, fused gates + epilogue ----------------
// grid 64 (16 h-cols each), block 384 (6 waves: ih r/z/n, hh r/z/n).
__global__ __launch_bounds__(384, 1) void k_gru(
    const unsigned short* __restrict__ xhi, const unsigned short* __restrict__ xlo,
    const unsigned short* __restrict__ hhi_s, const unsigned short* __restrict__ hlo_s,
    const float* __restrict__ hsrc,
    const float* __restrict__ wih, const float* __restrict__ whh,
    const float* __restrict__ bih, const float* __restrict__ bhh,
    float* __restrict__ hdst, unsigned short* __restrict__ hhi_d,
    unsigned short* __restrict__ hlo_d) {
  __shared__ float glds[6][64][17];                // padded: epilogue reads 2-way free
  const int tid = threadIdx.x, blk = blockIdx.x;
  const int lane = tid & 63, wv = tid >> 6;        // wv in [0,6)
  const int j0 = blk * 16;
  {
    const int g = wv - (wv >= 3 ? 3 : 0);          // gate r/z/n
    const bool hhp = wv >= 3;
    const unsigned short* Ahi = hhp ? hhi_s : xhi;
    const unsigned short* Alo = hhp ? hlo_s : xlo;
    const float* W = (hhp ? whh : wih) + (size_t)(g * HH + j0) * HH;
    const int cl = lane & 15, kk = (lane >> 4) * 8;
    f32x4 acc[4];
    acc[0] = acc[1] = acc[2] = acc[3] = (f32x4){0.f, 0.f, 0.f, 0.f};
    for (int k0 = 0; k0 < HH; k0 += 32) {
      const float* wp = W + (size_t)cl * HH + k0 + kk;
      const f32x4 w0 = *(const f32x4*)wp;
      const f32x4 w1 = *(const f32x4*)(wp + 4);
      union { unsigned short u[8]; bf16x8 b; } chi, clo;
      #pragma unroll
      for (int u2 = 0; u2 < 4; ++u2) {
        const unsigned ua = __float_as_uint(w0[u2]);
        chi.u[u2] = (unsigned short)(ua >> 16);
        clo.u[u2] = (unsigned short)(__float_as_uint(w0[u2] - __uint_as_float(ua & 0xFFFF0000u)) >> 16);
        const unsigned ub = __float_as_uint(w1[u2]);
        chi.u[4 + u2] = (unsigned short)(ub >> 16);
        clo.u[4 + u2] = (unsigned short)(__float_as_uint(w1[u2] - __uint_as_float(ub & 0xFFFF0000u)) >> 16);
      }
      #pragma unroll
      for (int rt = 0; rt < 4; ++rt) {
        const size_t aoff = (size_t)(rt * 16 + cl) * HH + k0 + kk;
        const bf16x8 ah = *(const bf16x8*)(Ahi + aoff);
        const bf16x8 al = *(const bf16x8*)(Alo + aoff);
        acc[rt] = __builtin_amdgcn_mfma_f32_16x16x32_bf16(ah, chi.b, acc[rt], 0, 0, 0);
        acc[rt] = __builtin_amdgcn_mfma_f32_16x16x32_bf16(al, chi.b, acc[rt], 0, 0, 0);
        acc[rt] = __builtin_amdgcn_mfma_f32_16x16x32_bf16(ah, clo.b, acc[rt], 0, 0, 0);
      }
    }
    #pragma unroll
    for (int rt = 0; rt < 4; ++rt)
      #pragma unroll
      for (int rg = 0; rg < 4; ++rg)
        glds[wv][rt * 16 + (lane >> 4) * 4 + rg][cl] = acc[rt][rg];
  }
  __syncthreads();
  if (tid < 256) {
    const int b = tid & 63, c0 = tid >> 6;
    #pragma unroll
    for (int ci = 0; ci < 4; ++ci) {
      const int c = c0 + 4 * ci;
      const int j = j0 + c;
      const float gir = glds[0][b][c] + bih[j];
      const float giz = glds[1][b][c] + bih[HH + j];
      const float gin = glds[2][b][c] + bih[2 * HH + j];
      const float ghr = glds[3][b][c] + bhh[j];
      const float ghz = glds[4][b][c] + bhh[HH + j];
      const float ghn = glds[5][b][c] + bhh[2 * HH + j];
      const float r_ = 1.f / (1.f + __expf(-(gir + ghr)));
      const float z_ = 1.f / (1.f + __expf(-(giz + ghz)));
      const float n_ = tanhf(gin + r_ * ghn);
      const float hold = hsrc[(size_t)b * HH + j];
      const float hnew = (1.f - z_) * n_ + z_ * hold;
      hdst[(size_t)b * HH + j] = hnew;
      const unsigned short hh16 = f2bf(hnew);
      hhi_d[(size_t)b * HH + j] = hh16;
      hlo_d[(size_t)b * HH + j] = f2bf(hnew - bf2f(hh16));
    }
  }
}

// ---------------- logits = h @ w_out^T + b_out (bf16 MFMA, LDS-free) ----------------
// grid 500, block 128 (2 waves x 32 cols). A (h, 128 KB) read straight from L2.
__global__ __launch_bounds__(128) void k_logits(
    const unsigned short* __restrict__ hb, const unsigned short* __restrict__ wbf,
    const float* __restrict__ wout, const float* __restrict__ bout,
    float* __restrict__ lbuf, int cachew) {
  const int tid = threadIdx.x, blk = blockIdx.x;
  const int lane = tid & 63, wv = tid >> 6;        // 2 waves
  const int n0 = blk * 64 + wv * 32;
  const int cl = lane & 15, kk = (lane >> 4) * 8;
  f32x4 acc[4][2];
  #pragma unroll
  for (int i = 0; i < 4; ++i) acc[i][0] = acc[i][1] = (f32x4){0.f, 0.f, 0.f, 0.f};

  for (int k0 = 0; k0 < HH; k0 += 32) {
    bf16x8 bfr[2];
    #pragma unroll
    for (int ct = 0; ct < 2; ++ct) {
      const size_t boff = (size_t)(n0 + ct * 16 + cl) * HH + k0 + kk;
      if (cachew) {
        bfr[ct] = *(const bf16x8*)(wbf + boff);
      } else {
        const f32x4 w0 = *(const f32x4*)(wout + boff);
        const f32x4 w1 = *(const f32x4*)(wout + boff + 4);
        union { unsigned short u[8]; bf16x8 b; } cv;
        #pragma unroll
        for (int u2 = 0; u2 < 4; ++u2) { cv.u[u2] = f2bf(w0[u2]); cv.u[4 + u2] = f2bf(w1[u2]); }
        bfr[ct] = cv.b;
      }
    }
    #pragma unroll
    for (int rt = 0; rt < 4; ++rt) {
      const bf16x8 afr = *(const bf16x8*)(hb + (size_t)(rt * 16 + cl) * HH + k0 + kk);
      acc[rt][0] = __builtin_amdgcn_mfma_f32_16x16x32_bf16(afr, bfr[0], acc[rt][0], 0, 0, 0);
      acc[rt][1] = __builtin_amdgcn_mfma_f32_16x16x32_bf16(afr, bfr[1], acc[rt][1], 0, 0, 0);
    }
  }
  #pragma unroll
  for (int ct = 0; ct < 2; ++ct) {
    const int col = n0 + ct * 16 + cl;
    const float bo = bout[col];
    #pragma unroll
    for (int rt = 0; rt < 4; ++rt)
      #pragma unroll
      for (int rg = 0; rg < 4; ++rg) {
        const int row = rt * 16 + (lane >> 4) * 4 + rg;
        lbuf[(size_t)row * VV + col] = acc[rt][ct][rg] + bo;
      }
  }
}

// ---------------- two-pass logsumexp + exact argmax recheck + out + next-x ----------------
// grid 64 (one block per batch row), block 1024.
__global__ __launch_bounds__(1024, 1) void k_reduce(
    const float* __restrict__ lbuf, const float* __restrict__ wout,
    const float* __restrict__ bout, const float* __restrict__ emb,
    const float* __restrict__ hnew, const float* __restrict__ hfin,
    float* __restrict__ out, unsigned short* __restrict__ xhi,
    unsigned short* __restrict__ xlo, int t) {
  __shared__ struct {
    float rowc[VV];
    float m[16]; int idx[16]; float s[16];
    float M, LZ; int cnt, tok; int cand[62];
  } sm;
  const int tid = threadIdx.x, b = blockIdx.x;
  const int lane = tid & 63, wv = tid >> 6;
  const f32x4* row4 = (const f32x4*)(lbuf + (size_t)b * VV);
  f32x4* rowc4 = (f32x4*)sm.rowc;

  // pass A: cache row in LDS + max/argmax (first-max tie-break)
  float m = -3.0e38f; int idx = 0x7fffffff;
  for (int i = tid; i < VV / 4; i += 1024) {
    const f32x4 v = row4[i];
    rowc4[i] = v;
    #pragma unroll
    for (int u = 0; u < 4; ++u)
      if (v[u] > m) { m = v[u]; idx = 4 * i + u; }
  }
  #pragma unroll
  for (int d = 1; d < 64; d <<= 1) {
    const float om = __shfl_xor(m, d, 64);
    const int oi = __shfl_xor(idx, d, 64);
    if (om > m || (om == m && oi < idx)) { m = om; idx = oi; }
  }
  if (lane == 0) { sm.m[wv] = m; sm.idx[wv] = idx; }
  __syncthreads();
  if (tid == 0) {
    float M = sm.m[0]; int I = sm.idx[0];
    for (int w = 1; w < 16; ++w)
      if (sm.m[w] > M || (sm.m[w] == M && sm.idx[w] < I)) { M = sm.m[w]; I = sm.idx[w]; }
    sm.M = M; sm.tok = I; sm.cnt = 0;
  }
  __syncthreads();
  const float M = sm.M;

  // pass B: sum exp(x - M)
  float s = 0.f;
  for (int i = tid; i < VV / 4; i += 1024) {
    const f32x4 v = rowc4[i];
    s += __expf(v[0] - M) + __expf(v[1] - M) + __expf(v[2] - M) + __expf(v[3] - M);
  }
  #pragma unroll
  for (int d = 1; d < 64; d <<= 1) s += __shfl_xor(s, d, 64);
  if (lane == 0) sm.s[wv] = s;
  __syncthreads();
  if (tid == 0) {
    float S = 0.f;
    for (int w = 0; w < 16; ++w) S += sm.s[w];
    sm.LZ = M + logf(S);
  }
  __syncthreads();

  if (t < TT - 1) {
    const float thr = M - 0.05f;                   // candidate band
    for (int i = tid; i < VV / 4; i += 1024) {
      const f32x4 v = rowc4[i];
      #pragma unroll
      for (int u = 0; u < 4; ++u)
        if (v[u] >= thr) {
          const int c = atomicAdd(&sm.cnt, 1);
          if (c < 62) sm.cand[c] = 4 * i + u;
        }
    }
    __syncthreads();
    if (wv == 0) {                                 // exact f32 recheck
      const int nc = sm.cnt < 62 ? sm.cnt : 62;
      const float* hrow = hnew + (size_t)b * HH;
      f32x4 h4[4];
      #pragma unroll
      for (int u = 0; u < 4; ++u) h4[u] = *(const f32x4*)(hrow + lane * 16 + u * 4);
      float best = -3.0e38f; int bi = 0x7fffffff;
      for (int ci = 0; ci < nc; ++ci) {
        const int v = sm.cand[ci];
        const float* wrow = wout + (size_t)v * HH + lane * 16;
        float ss = 0.f;
        #pragma unroll
        for (int u = 0; u < 4; ++u) {
          const f32x4 w4 = *(const f32x4*)(wrow + u * 4);
          ss += h4[u][0] * w4[0] + h4[u][1] * w4[1] + h4[u][2] * w4[2] + h4[u][3] * w4[3];
        }
        #pragma unroll
        for (int d = 1; d < 64; d <<= 1) ss += __shfl_xor(ss, d, 64);
        ss += bout[v];
        if (ss > best || (ss == best && v < bi)) { best = ss; bi = v; }
      }
      if (lane == 0) sm.tok = bi;
    }
    __syncthreads();
    const int tok = sm.tok;                        // next x + splits
    float e = emb[(size_t)tok * HH + tid];
    e = e > 0.f ? e : 0.f;
    const unsigned short eh = f2bf(e);
    xhi[(size_t)b * HH + tid] = eh;
    xlo[(size_t)b * HH + tid] = f2bf(e - bf2f(eh));
  }

  const float lz = sm.LZ;                          // log_softmax + store
  f32x4* out4 = (f32x4*)(out + ((size_t)b * TT + t) * VV);
  for (int i = tid; i < VV / 4; i += 1024) {
    const f32x4 v = rowc4[i];
    out4[i] = v - lz;
  }
  if (t == TT - 1)
    out[(size_t)BB * TT * VV + (size_t)b * HH + tid] = hfin[(size_t)b * HH + tid];
}

extern "C" void kernel_launch(void* const* d_in, const int* in_sizes, int n_in,
                              void* d_out, int out_size, void* d_ws, size_t ws_size,
                              hipStream_t stream) {
  const float* enc  = (const float*)d_in[1];
  const float* emb  = (const float*)d_in[2];
  const float* wih  = (const float*)d_in[3];
  const float* whh  = (const float*)d_in[4];
  const float* bih  = (const float*)d_in[5];
  const float* bhh  = (const float*)d_in[6];
  const float* wout = (const float*)d_in[7];
  const float* bout = (const float*)d_in[8];
  float* out = (float*)d_out;

  char* ws = (char*)d_ws;
  size_t off = 0;
  float* hrm = (float*)(ws + off);                   off += (size_t)2 * BB * HH * 4;
  unsigned short* hhi = (unsigned short*)(ws + off); off += (size_t)2 * BB * HH * 2;
  unsigned short* hlo = (unsigned short*)(ws + off); off += (size_t)2 * BB * HH * 2;
  unsigned short* xhi = (unsigned short*)(ws + off); off += (size_t)BB * HH * 2;
  unsigned short* xlo = (unsigned short*)(ws + off); off += (size_t)BB * HH * 2;
  float* lbuf = (float*)(ws + off);                  off += (size_t)BB * VV * 4;
  unsigned short* wbf = (unsigned short*)(ws + off);
  const int cachew = (ws_size >= off + (size_t)VV * HH * 2) ? 1 : 0;

  hipLaunchKernelGGL(k_init, dim3(64), dim3(1024), 0, stream,
                     enc, emb, hrm, hhi, hlo, xhi, xlo);
  if (cachew)
    hipLaunchKernelGGL(k_wconv, dim3(2048), dim3(256), 0, stream, wout, wbf);

  for (int t = 0; t < TT; ++t) {
    const int p = t & 1;
    const float* hsrc = hrm + (size_t)p * BB * HH;
    float* hdst = hrm + (size_t)(p ^ 1) * BB * HH;
    const unsigned short* hhs = hhi + (size_t)p * BB * HH;
    const unsigned short* hls = hlo + (size_t)p * BB * HH;
    unsigned short* hhd = hhi + (size_t)(p ^ 1) * BB * HH;
    unsigned short* hld = hlo + (size_t)(p ^ 1) * BB * HH;
    hipLaunchKernelGGL(k_gru, dim3(64), dim3(384), 0, stream,
                       xhi, xlo, hhs, hls, hsrc, wih, whh, bih, bhh, hdst, hhd, hld);
    hipLaunchKernelGGL(k_logits, dim3(500), dim3(128), 0, stream,
                       hhd, wbf, wout, bout, lbuf, cachew);
    hipLaunchKernelGGL(k_reduce, dim3(64), dim3(1024), 0, stream,
                       lbuf, wout, bout, emb, hdst, hrm + (size_t)BB * HH,
                       out, xhi, xlo, t);
  }
}

// Round 4
// 1381.034 us; speedup vs baseline: 5.3025x; 1.2661x over previous
//
#include <hip/hip_runtime.h>
#include <math.h>

#define BB 64
#define HH 1024
#define VV 32000
#define TT 13
#define QS 8000            // VV/4 per quarter

typedef float f32x4 __attribute__((ext_vector_type(4)));
typedef __bf16 bf16x8 __attribute__((ext_vector_type(8)));

__device__ __forceinline__ unsigned short f2bf(float f) {   // RNE
  unsigned u = __float_as_uint(f);
  u = (u + 0x7fffu + ((u >> 16) & 1u)) >> 16;
  return (unsigned short)u;
}
__device__ __forceinline__ float bf2f(unsigned short s) {
  return __uint_as_float(((unsigned)s) << 16);
}

// ---------------- init ----------------
__global__ __launch_bounds__(1024) void k_init(
    const float* __restrict__ enc, const float* __restrict__ emb,
    float* __restrict__ hrm, unsigned short* __restrict__ hhi,
    unsigned short* __restrict__ hlo, unsigned short* __restrict__ xhi,
    unsigned short* __restrict__ xlo) {
  const int g = blockIdx.x * 1024 + threadIdx.x;
  const float h = enc[g];
  hrm[g] = h;
  const unsigned short h16 = f2bf(h);
  hhi[g] = h16;
  hlo[g] = f2bf(h - bf2f(h16));
  float e = emb[threadIdx.x];
  e = e > 0.f ? e : 0.f;
  const unsigned short e16 = f2bf(e);
  xhi[g] = e16;
  xlo[g] = f2bf(e - bf2f(e16));
}

// ---------------- one-time w_out -> bf16 ----------------
__global__ __launch_bounds__(256) void k_wconv(const float* __restrict__ w,
                                               unsigned short* __restrict__ o) {
  const int n4 = VV * HH / 4;
  for (int i = blockIdx.x * 256 + threadIdx.x; i < n4; i += gridDim.x * 256) {
    const f32x4 v = ((const f32x4*)w)[i];
    ushort4 u;
    u.x = f2bf(v[0]); u.y = f2bf(v[1]); u.z = f2bf(v[2]); u.w = f2bf(v[3]);
    ((ushort4*)o)[i] = u;
  }
}

// ---------------- one-time wih/whh -> bf16 hi/lo split cache ----------------
// layout: row r = g6*HH + j  (g6<3 -> wih gate g6; g6>=3 -> whh gate g6-3)
__global__ __launch_bounds__(256) void k_wconv2(
    const float* __restrict__ wih, const float* __restrict__ whh,
    unsigned short* __restrict__ ghi, unsigned short* __restrict__ glo) {
  const int n4 = 6 * HH * HH / 4;
  for (int i = blockIdx.x * 256 + threadIdx.x; i < n4; i += gridDim.x * 256) {
    const int flat = i * 4;
    const float* src = flat < 3 * HH * HH ? wih + flat : whh + (flat - 3 * HH * HH);
    const f32x4 v = *(const f32x4*)src;
    ushort4 hi, lo;
    hi.x = f2bf(v[0]); lo.x = f2bf(v[0] - bf2f(hi.x));
    hi.y = f2bf(v[1]); lo.y = f2bf(v[1] - bf2f(hi.y));
    hi.z = f2bf(v[2]); lo.z = f2bf(v[2] - bf2f(hi.z));
    hi.w = f2bf(v[3]); lo.w = f2bf(v[3] - bf2f(hi.w));
    ((ushort4*)ghi)[i] = hi;
    ((ushort4*)glo)[i] = lo;
  }
}

// ---------------- GRU gates: split-bf16 MFMA, 384 one-wave blocks ----------------
// blk -> (g6 = blk%6, jt = blk/6). Writes gbuf[g6][BB][HH] (pre-bias gate dots).
__global__ __launch_bounds__(64) void k_gru(
    const unsigned short* __restrict__ xhi, const unsigned short* __restrict__ xlo,
    const unsigned short* __restrict__ hhi_s, const unsigned short* __restrict__ hlo_s,
    const unsigned short* __restrict__ ghi, const unsigned short* __restrict__ glo,
    const float* __restrict__ wih, const float* __restrict__ whh,
    float* __restrict__ gbuf, int cachegw) {
  const int blk = blockIdx.x, lane = threadIdx.x;
  const int g6 = blk % 6, jt = blk / 6;
  const unsigned short* Ahi = g6 < 3 ? xhi : hhi_s;
  const unsigned short* Alo = g6 < 3 ? xlo : hlo_s;
  const int cl = lane & 15, kk = (lane >> 4) * 8;
  const int j = jt * 16 + cl;
  f32x4 acc[4];
  acc[0] = acc[1] = acc[2] = acc[3] = (f32x4){0.f, 0.f, 0.f, 0.f};

  if (cachegw) {
    const unsigned short* bh = ghi + (size_t)(g6 * HH + j) * HH;
    const unsigned short* bl = glo + (size_t)(g6 * HH + j) * HH;
    #pragma unroll 4
    for (int k0 = 0; k0 < HH; k0 += 32) {
      const bf16x8 whi = *(const bf16x8*)(bh + k0 + kk);
      const bf16x8 wlo = *(const bf16x8*)(bl + k0 + kk);
      #pragma unroll
      for (int rt = 0; rt < 4; ++rt) {
        const size_t aoff = (size_t)(rt * 16 + cl) * HH + k0 + kk;
        const bf16x8 ah = *(const bf16x8*)(Ahi + aoff);
        const bf16x8 al = *(const bf16x8*)(Alo + aoff);
        acc[rt] = __builtin_amdgcn_mfma_f32_16x16x32_bf16(ah, whi, acc[rt], 0, 0, 0);
        acc[rt] = __builtin_amdgcn_mfma_f32_16x16x32_bf16(al, whi, acc[rt], 0, 0, 0);
        acc[rt] = __builtin_amdgcn_mfma_f32_16x16x32_bf16(ah, wlo, acc[rt], 0, 0, 0);
      }
    }
  } else {
    const float* W = (g6 < 3 ? wih : whh) + (size_t)((g6 % 3) * HH + j) * HH;
    for (int k0 = 0; k0 < HH; k0 += 32) {
      const f32x4 w0 = *(const f32x4*)(W + k0 + kk);
      const f32x4 w1 = *(const f32x4*)(W + k0 + kk + 4);
      union { unsigned short u[8]; bf16x8 b; } chi, clo;
      #pragma unroll
      for (int u2 = 0; u2 < 4; ++u2) {
        chi.u[u2] = f2bf(w0[u2]); clo.u[u2] = f2bf(w0[u2] - bf2f(chi.u[u2]));
        chi.u[4 + u2] = f2bf(w1[u2]); clo.u[4 + u2] = f2bf(w1[u2] - bf2f(chi.u[4 + u2]));
      }
      #pragma unroll
      for (int rt = 0; rt < 4; ++rt) {
        const size_t aoff = (size_t)(rt * 16 + cl) * HH + k0 + kk;
        const bf16x8 ah = *(const bf16x8*)(Ahi + aoff);
        const bf16x8 al = *(const bf16x8*)(Alo + aoff);
        acc[rt] = __builtin_amdgcn_mfma_f32_16x16x32_bf16(ah, chi.b, acc[rt], 0, 0, 0);
        acc[rt] = __builtin_amdgcn_mfma_f32_16x16x32_bf16(al, chi.b, acc[rt], 0, 0, 0);
        acc[rt] = __builtin_amdgcn_mfma_f32_16x16x32_bf16(ah, clo.b, acc[rt], 0, 0, 0);
      }
    }
  }
  #pragma unroll
  for (int rt = 0; rt < 4; ++rt)
    #pragma unroll
    for (int rg = 0; rg < 4; ++rg) {
      const int row = rt * 16 + (lane >> 4) * 4 + rg;
      gbuf[(size_t)(g6 * BB + row) * HH + jt * 16 + cl] = acc[rt][rg];
    }
}

// ---------------- GRU epilogue: nonlinearity + h splits ----------------
__global__ __launch_bounds__(1024) void k_gep(
    const float* __restrict__ gbuf, const float* __restrict__ bih,
    const float* __restrict__ bhh, const float* __restrict__ hsrc,
    float* __restrict__ hdst, unsigned short* __restrict__ hhi_d,
    unsigned short* __restrict__ hlo_d) {
  const int b = blockIdx.x, j = threadIdx.x;
  const size_t base = (size_t)b * HH + j;
  const float gir = gbuf[(size_t)(0 * BB + b) * HH + j] + bih[j];
  const float giz = gbuf[(size_t)(1 * BB + b) * HH + j] + bih[HH + j];
  const float gin = gbuf[(size_t)(2 * BB + b) * HH + j] + bih[2 * HH + j];
  const float ghr = gbuf[(size_t)(3 * BB + b) * HH + j] + bhh[j];
  const float ghz = gbuf[(size_t)(4 * BB + b) * HH + j] + bhh[HH + j];
  const float ghn = gbuf[(size_t)(5 * BB + b) * HH + j] + bhh[2 * HH + j];
  const float r_ = 1.f / (1.f + __expf(-(gir + ghr)));
  const float z_ = 1.f / (1.f + __expf(-(giz + ghz)));
  const float n_ = tanhf(gin + r_ * ghn);
  const float hnew = (1.f - z_) * n_ + z_ * hsrc[base];
  hdst[base] = hnew;
  const unsigned short h16 = f2bf(hnew);
  hhi_d[base] = h16;
  hlo_d[base] = f2bf(hnew - bf2f(h16));
}

// ---------------- logits: bf16 MFMA, 500 blocks x 4 waves x 16 cols ----------------
__global__ __launch_bounds__(256) void k_logits(
    const unsigned short* __restrict__ hb, const unsigned short* __restrict__ wbf,
    const float* __restrict__ wout, const float* __restrict__ bout,
    float* __restrict__ lbuf, int cachew) {
  const int tid = threadIdx.x, blk = blockIdx.x;
  const int lane = tid & 63, wv = tid >> 6;
  const int n0 = blk * 64 + wv * 16;
  const int cl = lane & 15, kk = (lane >> 4) * 8;
  f32x4 acc[4];
  acc[0] = acc[1] = acc[2] = acc[3] = (f32x4){0.f, 0.f, 0.f, 0.f};

  if (cachew) {
    const unsigned short* wrow = wbf + (size_t)(n0 + cl) * HH;
    #pragma unroll 2
    for (int k0 = 0; k0 < HH; k0 += 32) {
      const bf16x8 bfr = *(const bf16x8*)(wrow + k0 + kk);
      #pragma unroll
      for (int rt = 0; rt < 4; ++rt) {
        const bf16x8 afr = *(const bf16x8*)(hb + (size_t)(rt * 16 + cl) * HH + k0 + kk);
        acc[rt] = __builtin_amdgcn_mfma_f32_16x16x32_bf16(afr, bfr, acc[rt], 0, 0, 0);
      }
    }
  } else {
    const float* wrow = wout + (size_t)(n0 + cl) * HH;
    for (int k0 = 0; k0 < HH; k0 += 32) {
      const f32x4 w0 = *(const f32x4*)(wrow + k0 + kk);
      const f32x4 w1 = *(const f32x4*)(wrow + k0 + kk + 4);
      union { unsigned short u[8]; bf16x8 b; } cv;
      #pragma unroll
      for (int u2 = 0; u2 < 4; ++u2) { cv.u[u2] = f2bf(w0[u2]); cv.u[4 + u2] = f2bf(w1[u2]); }
      #pragma unroll
      for (int rt = 0; rt < 4; ++rt) {
        const bf16x8 afr = *(const bf16x8*)(hb + (size_t)(rt * 16 + cl) * HH + k0 + kk);
        acc[rt] = __builtin_amdgcn_mfma_f32_16x16x32_bf16(afr, cv.b, acc[rt], 0, 0, 0);
      }
    }
  }
  const int col = n0 + cl;
  const float bo = bout[col];
  #pragma unroll
  for (int rt = 0; rt < 4; ++rt)
    #pragma unroll
    for (int rg = 0; rg < 4; ++rg) {
      const int row = rt * 16 + (lane >> 4) * 4 + rg;
      lbuf[(size_t)row * VV + col] = acc[rt][rg] + bo;
    }
}

// ---------------- quarter-row max + sumexp + candidates ----------------
// grid 256: blk -> (b = blk>>2, q = blk&3). Deterministic (per-set candidates).
__global__ __launch_bounds__(256) void k_sum(
    const float* __restrict__ lbuf, float* __restrict__ mq, float* __restrict__ sq,
    int* __restrict__ candcnt, int* __restrict__ candidx, float* __restrict__ candval) {
  __shared__ float srow[QS];
  __shared__ float red[4];
  __shared__ int icnt;
  const int tid = threadIdx.x;
  const int b = blockIdx.x >> 2, q = blockIdx.x & 3;
  const int lane = tid & 63, wv = tid >> 6;
  const f32x4* src = (const f32x4*)(lbuf + (size_t)b * VV + q * QS);
  f32x4* s4 = (f32x4*)srow;

  float m = -3.0e38f;
  for (int i = tid; i < QS / 4; i += 256) {
    const f32x4 v = src[i];
    s4[i] = v;
    m = fmaxf(fmaxf(fmaxf(m, v[0]), v[1]), fmaxf(v[2], v[3]));
  }
  #pragma unroll
  for (int d = 1; d < 64; d <<= 1) m = fmaxf(m, __shfl_xor(m, d, 64));
  if (lane == 0) red[wv] = m;
  if (tid == 0) icnt = 0;
  __syncthreads();
  const float M = fmaxf(fmaxf(red[0], red[1]), fmaxf(red[2], red[3]));

  float s = 0.f;
  for (int i = tid; i < QS / 4; i += 256) {
    const f32x4 v = s4[i];
    s += __expf(v[0] - M) + __expf(v[1] - M) + __expf(v[2] - M) + __expf(v[3] - M);
  }
  #pragma unroll
  for (int d = 1; d < 64; d <<= 1) s += __shfl_xor(s, d, 64);
  __syncthreads();
  if (lane == 0) red[wv] = s;
  __syncthreads();
  if (tid == 0) {
    mq[b * 4 + q] = M;
    sq[b * 4 + q] = red[0] + red[1] + red[2] + red[3];
  }

  const float thr = M - 0.05f;
  for (int i = tid; i < QS / 4; i += 256) {
    const f32x4 v = s4[i];
    #pragma unroll
    for (int u = 0; u < 4; ++u)
      if (v[u] >= thr) {
        const int c = atomicAdd(&icnt, 1);
        if (c < 16) {
          candidx[(b * 4 + q) * 16 + c] = q * QS + 4 * i + u;
          candval[(b * 4 + q) * 16 + c] = v[u];
        }
      }
  }
  __syncthreads();
  if (tid == 0) candcnt[b * 4 + q] = icnt < 16 ? icnt : 16;
}

// ---------------- logZ combine + out write + exact argmax recheck + next x ----------------
// grid 256: blk -> (b, q). q==0 block does recheck + x (t<12) or h_final (t==12).
__global__ __launch_bounds__(256) void k_out(
    const float* __restrict__ lbuf, const float* __restrict__ mq,
    const float* __restrict__ sq, const int* __restrict__ candcnt,
    const int* __restrict__ candidx, const float* __restrict__ candval,
    const float* __restrict__ wout, const float* __restrict__ bout,
    const float* __restrict__ emb, const float* __restrict__ hnew,
    float* __restrict__ out, unsigned short* __restrict__ xhi,
    unsigned short* __restrict__ xlo, int t) {
  __shared__ int stok;
  const int tid = threadIdx.x;
  const int b = blockIdx.x >> 2, q = blockIdx.x & 3;

  const float m0 = mq[b * 4 + 0], m1 = mq[b * 4 + 1];
  const float m2 = mq[b * 4 + 2], m3 = mq[b * 4 + 3];
  const float M = fmaxf(fmaxf(m0, m1), fmaxf(m2, m3));
  const float S = sq[b * 4 + 0] * __expf(m0 - M) + sq[b * 4 + 1] * __expf(m1 - M) +
                  sq[b * 4 + 2] * __expf(m2 - M) + sq[b * 4 + 3] * __expf(m3 - M);
  const float LZ = M + logf(S);

  const f32x4* src = (const f32x4*)(lbuf + (size_t)b * VV + q * QS);
  f32x4* dst = (f32x4*)(out + ((size_t)b * TT + t) * VV + q * QS);
  for (int i = tid; i < QS / 4; i += 256) {
    const f32x4 v = src[i];
    dst[i] = v - LZ;
  }

  if (q == 0 && t < TT - 1) {
    if (tid < 64) {
      const int q2 = tid >> 4, c = tid & 15;
      const int cc = candcnt[b * 4 + q2];
      int vidx = 0;
      bool valid = c < cc;
      if (valid) {
        vidx = candidx[(b * 4 + q2) * 16 + c];
        valid = candval[(b * 4 + q2) * 16 + c] >= M - 0.05f;
      }
      unsigned long long mask = __ballot(valid);
      f32x4 h4[4];
      #pragma unroll
      for (int u = 0; u < 4; ++u)
        h4[u] = *(const f32x4*)(hnew + (size_t)b * HH + tid * 16 + u * 4);
      float best = -3.0e38f; int bi = 0x7fffffff;
      while (mask) {
        const int l = __ffsll((unsigned long long)mask) - 1;
        mask &= mask - 1;
        const int v = __shfl(vidx, l, 64);
        const float* wrow = wout + (size_t)v * HH + tid * 16;
        float ss = 0.f;
        #pragma unroll
        for (int u = 0; u < 4; ++u) {
          const f32x4 w4 = *(const f32x4*)(wrow + u * 4);
          ss += h4[u][0] * w4[0] + h4[u][1] * w4[1] + h4[u][2] * w4[2] + h4[u][3] * w4[3];
        }
        #pragma unroll
        for (int d = 1; d < 64; d <<= 1) ss += __shfl_xor(ss, d, 64);
        ss += bout[v];
        if (ss > best || (ss == best && v < bi)) { best = ss; bi = v; }
      }
      if (tid == 0) stok = bi;
    }
    __syncthreads();
    const int tok = stok;
    for (int j = tid; j < HH; j += 256) {
      float e = emb[(size_t)tok * HH + j];
      e = e > 0.f ? e : 0.f;
      const unsigned short e16 = f2bf(e);
      xhi[(size_t)b * HH + j] = e16;
      xlo[(size_t)b * HH + j] = f2bf(e - bf2f(e16));
    }
  }
  if (q == 0 && t == TT - 1) {
    for (int j = tid; j < HH; j += 256)
      out[(size_t)BB * TT * VV + (size_t)b * HH + j] = hnew[(size_t)b * HH + j];
  }
}

extern "C" void kernel_launch(void* const* d_in, const int* in_sizes, int n_in,
                              void* d_out, int out_size, void* d_ws, size_t ws_size,
                              hipStream_t stream) {
  const float* enc  = (const float*)d_in[1];
  const float* emb  = (const float*)d_in[2];
  const float* wih  = (const float*)d_in[3];
  const float* whh  = (const float*)d_in[4];
  const float* bih  = (const float*)d_in[5];
  const float* bhh  = (const float*)d_in[6];
  const float* wout = (const float*)d_in[7];
  const float* bout = (const float*)d_in[8];
  float* out = (float*)d_out;

  char* ws = (char*)d_ws;
  size_t off = 0;
  auto alloc = [&](size_t bytes) -> char* {
    char* p = ws + off;
    off += (bytes + 255) & ~(size_t)255;
    return p;
  };
  float* hrm = (float*)alloc((size_t)2 * BB * HH * 4);
  unsigned short* hhi = (unsigned short*)alloc((size_t)2 * BB * HH * 2);
  unsigned short* hlo = (unsigned short*)alloc((size_t)2 * BB * HH * 2);
  unsigned short* xhi = (unsigned short*)alloc((size_t)BB * HH * 2);
  unsigned short* xlo = (unsigned short*)alloc((size_t)BB * HH * 2);
  float* gbuf = (float*)alloc((size_t)6 * BB * HH * 4);
  float* lbuf = (float*)alloc((size_t)BB * VV * 4);
  float* mq = (float*)alloc((size_t)BB * 4 * 4);
  float* sq = (float*)alloc((size_t)BB * 4 * 4);
  int* candcnt = (int*)alloc((size_t)BB * 4 * 4);
  int* candidx = (int*)alloc((size_t)BB * 4 * 16 * 4);
  float* candval = (float*)alloc((size_t)BB * 4 * 16 * 4);
  unsigned short* wbf = (unsigned short*)alloc((size_t)VV * HH * 2);
  const int cachew = (ws_size >= off) ? 1 : 0;
  unsigned short* ghi = (unsigned short*)alloc((size_t)6 * HH * HH * 2);
  unsigned short* glo = (unsigned short*)alloc((size_t)6 * HH * HH * 2);
  const int cachegw = (ws_size >= off) ? 1 : 0;

  hipLaunchKernelGGL(k_init, dim3(64), dim3(1024), 0, stream,
                     enc, emb, hrm, hhi, hlo, xhi, xlo);
  if (cachew)
    hipLaunchKernelGGL(k_wconv, dim3(2048), dim3(256), 0, stream, wout, wbf);
  if (cachegw)
    hipLaunchKernelGGL(k_wconv2, dim3(1024), dim3(256), 0, stream, wih, whh, ghi, glo);

  for (int t = 0; t < TT; ++t) {
    const int p = t & 1;
    const float* hsrc = hrm + (size_t)p * BB * HH;
    float* hdst = hrm + (size_t)(p ^ 1) * BB * HH;
    const unsigned short* hhs = hhi + (size_t)p * BB * HH;
    const unsigned short* hls = hlo + (size_t)p * BB * HH;
    unsigned short* hhd = hhi + (size_t)(p ^ 1) * BB * HH;
    unsigned short* hld = hlo + (size_t)(p ^ 1) * BB * HH;

    hipLaunchKernelGGL(k_gru, dim3(384), dim3(64), 0, stream,
                       xhi, xlo, hhs, hls, ghi, glo, wih, whh, gbuf, cachegw);
    hipLaunchKernelGGL(k_gep, dim3(64), dim3(1024), 0, stream,
                       gbuf, bih, bhh, hsrc, hdst, hhd, hld);
    hipLaunchKernelGGL(k_logits, dim3(500), dim3(256), 0, stream,
                       hhd, wbf, wout, bout, lbuf, cachew);
    hipLaunchKernelGGL(k_sum, dim3(256), dim3(256), 0, stream,
                       lbuf, mq, sq, candcnt, candidx, candval);
    hipLaunchKernelGGL(k_out, dim3(256), dim3(256), 0, stream,
                       lbuf, mq, sq, candcnt, candidx, candval,
                       wout, bout, emb, hdst, out, xhi, xlo, t);
  }
}